// Round 6
// baseline (583.643 us; speedup 1.0000x reference)
//
#include <hip/hip_runtime.h>

// GraphAttentionLayer on MI355X (gfx950)
// N=8192, IN_F=128, N_HID=64, OUT_F=128
//
// R6: fold the adj->bitmask pass INTO the attention K-loop.
//  - attn: 512 thr (8 waves x 16 Q-rows = 128 rows/block), grid 64 x C.
//    Triple staging, all double-buffered one iter ahead (1 barrier/iter):
//      * wht hi/lo -> LDS Bst (32 KB/iter, padded stride 72 u16)
//      * adj 128x128 tile -> regs (nontemporal dwordx4) -> packed bits ->
//        LDS Mbuf (2 KB/iter)  [replaces the separate 42us mask kernel]
//      * whcT B-frags register-pipelined from L2
//    adj is the only big HBM stream (256 MB total, read exactly once).
//  - proj: Whs/Wht bf16 hi+lo split + WhcT. combine: split-K merge (C=4).
//  - dur_us includes a ~400us harness floor (1 GB ws 0xAA poison + 256 MB
//    adj restore) we cannot affect; our kernels are proj+attn+combine.

#define NN 8192
#define INF_ 128
#define NHID 64
#define OUTF 128
#define NEGC -9.0e15f

typedef unsigned short u16;
typedef __attribute__((ext_vector_type(8))) short bf16x8;
typedef __attribute__((ext_vector_type(4))) float f32x4;
typedef __attribute__((ext_vector_type(4))) int i32x4;
typedef __attribute__((ext_vector_type(4))) unsigned u32x4;

static __device__ __forceinline__ u16 f2bf(float x) {
  union { float f; unsigned u; } v; v.f = x;
  unsigned lsb = (v.u >> 16) & 1u;
  v.u += 0x7fffu + lsb;            // round-to-nearest-even
  return (u16)(v.u >> 16);
}
static __device__ __forceinline__ float bf2f(u16 h) {
  union { float f; unsigned u; } v; v.u = ((unsigned)h) << 16;
  return v.f;
}
static __device__ __forceinline__ f32x4 mfma16(bf16x8 a, bf16x8 b, f32x4 c) {
  return __builtin_amdgcn_mfma_f32_16x16x32_bf16(a, b, c, 0, 0, 0);
}

// ---------------------------------------------------------------- kernel 1
__global__ __launch_bounds__(256) void proj_kernel(
    const float* __restrict__ h, const float* __restrict__ Ws,
    const float* __restrict__ Wt, const float* __restrict__ Wc,
    u16* __restrict__ whs_hi, u16* __restrict__ whs_lo,
    u16* __restrict__ wht_hi, u16* __restrict__ wht_lo,
    u16* __restrict__ whcT) {
  __shared__ f32x4 hbuf[8][32];   // 8 rows x 128 k
  const int tid = threadIdx.x;
  const int r0 = blockIdx.x * 8;
  hbuf[tid >> 5][tid & 31] =
      reinterpret_cast<const f32x4*>(h)[(size_t)r0 * 32 + tid];
  __syncthreads();

  float acc[8];
#pragma unroll
  for (int r = 0; r < 8; ++r) acc[r] = 0.f;

  if (tid < 128) {
    const float* W = (tid < 64) ? (Ws + tid) : (Wt + (tid - 64));
#pragma unroll 4
    for (int k4 = 0; k4 < 32; ++k4) {
      float w0 = W[(k4 * 4 + 0) * NHID];
      float w1 = W[(k4 * 4 + 1) * NHID];
      float w2 = W[(k4 * 4 + 2) * NHID];
      float w3 = W[(k4 * 4 + 3) * NHID];
#pragma unroll
      for (int r = 0; r < 8; ++r) {
        f32x4 hv = hbuf[r][k4];
        acc[r] += hv.x * w0 + hv.y * w1 + hv.z * w2 + hv.w * w3;
      }
    }
    const int col = tid & 63;
    u16* hi = (tid < 64) ? whs_hi : wht_hi;
    u16* lo = (tid < 64) ? whs_lo : wht_lo;
#pragma unroll
    for (int r = 0; r < 8; ++r) {
      float v = acc[r];
      u16 hb = f2bf(v);
      hi[(size_t)(r0 + r) * NHID + col] = hb;
      lo[(size_t)(r0 + r) * NHID + col] = f2bf(v - bf2f(hb));
    }
  } else {
    const int col = tid - 128;
    const float* W = Wc + col;
#pragma unroll 4
    for (int k4 = 0; k4 < 32; ++k4) {
      float w0 = W[(k4 * 4 + 0) * OUTF];
      float w1 = W[(k4 * 4 + 1) * OUTF];
      float w2 = W[(k4 * 4 + 2) * OUTF];
      float w3 = W[(k4 * 4 + 3) * OUTF];
#pragma unroll
      for (int r = 0; r < 8; ++r) {
        f32x4 hv = hbuf[r][k4];
        acc[r] += hv.x * w0 + hv.y * w1 + hv.z * w2 + hv.w * w3;
      }
    }
    union { u16 s[8]; u32x4 v; } pk;
#pragma unroll
    for (int r = 0; r < 8; ++r) pk.s[r] = f2bf(acc[r]);
    *reinterpret_cast<u32x4*>(whcT + (size_t)col * NN + r0) = pk.v;
  }
}

// ---------------------------------------------------------------- kernel 2
// 8 waves x 16 rows = 128 rows/block. chunk = blockIdx & (C-1),
// rb = blockIdx >> cshift. wht + adj-mask double-buffered one iter ahead.
__global__ __launch_bounds__(512, 2) void attn_kernel(
    const u16* __restrict__ whs_hi, const u16* __restrict__ whs_lo,
    const u16* __restrict__ wht_hi, const u16* __restrict__ wht_lo,
    const u16* __restrict__ whcT, const int* __restrict__ adj,
    float* __restrict__ Opart, float* __restrict__ mpart,
    float* __restrict__ lpart, float* __restrict__ out,
    int iters, int cshift, int final_write) {
  // staged wht: [buf][h][col*72 + k]  (stride 72 u16: b128 reads 2-way free)
  __shared__ __align__(16) u16 Bst[2][2][128 * 72];     // 72 KB
  // wave-private P: stride 136 u16 -> A-frag b128 reads 2-way free
  __shared__ __align__(16) u16 Pbuf[8][16][136];        // 34 KB
  // packed adj mask tile: [buf][row][colgrp] (uint4-read per row)
  __shared__ __align__(16) unsigned Mbuf[2][128][4];    // 4 KB

  const int tid = threadIdx.x;
  const int w = tid >> 6;
  const int lane = tid & 63;
  const int q = lane >> 4;
  const int ln = lane & 15;
  const int chunk = blockIdx.x & ((1 << cshift) - 1);
  const int rb = blockIdx.x >> cshift;
  const int rowB = rb * 128;
  const int row0 = rowB + w * 16;

  // wht staging role: (col, hi/lo, k-half)
  const int scol = tid >> 2;
  const int sh = (tid >> 1) & 1;
  const int shalf = tid & 1;
  const u16* sgbase = (sh ? wht_lo : wht_hi);
  u16* sdst0 = &Bst[0][sh][scol * 72 + shalf * 32];
  u16* sdst1 = &Bst[1][sh][scol * 72 + shalf * 32];
  // adj staging role: (row, 32-col group)
  const int arow = tid >> 2;
  const int acg = tid & 3;
  const int* agbase = adj + (size_t)(rowB + arow) * NN + acg * 32;

  // loop-invariant A-fragments (Whs rows row0+ln)
  bf16x8 a_hi[2], a_lo[2];
#pragma unroll
  for (int kh = 0; kh < 2; ++kh) {
    a_hi[kh] = *reinterpret_cast<const bf16x8*>(
        whs_hi + (size_t)(row0 + ln) * NHID + kh * 32 + q * 8);
    a_lo[kh] = *reinterpret_cast<const bf16x8*>(
        whs_lo + (size_t)(row0 + ln) * NHID + kh * 32 + q * 8);
  }

  f32x4 oacc[8];
#pragma unroll
  for (int ot = 0; ot < 8; ++ot)
#pragma unroll
    for (int g = 0; g < 4; ++g) oacc[ot][g] = 0.f;

  float m_old[4], l_run[4];
#pragma unroll
  for (int g = 0; g < 4; ++g) { m_old[g] = -__builtin_inff(); l_run[g] = 0.f; }

  const int jbase = chunk * iters;

  // ---- preload buf 0 (wht + packed adj mask)
  {
    const int j0 = jbase * 128;
    const u32x4* g4 = reinterpret_cast<const u32x4*>(
        sgbase + (size_t)(j0 + scol) * 64 + shalf * 32);
    u32x4 st0 = g4[0], st1 = g4[1], st2 = g4[2], st3 = g4[3];
    const i32x4* a4 = reinterpret_cast<const i32x4*>(agbase + j0);
    unsigned mw = 0;
#pragma unroll
    for (int i = 0; i < 8; ++i) {
      i32x4 v = __builtin_nontemporal_load(a4 + i);
      mw |= (v.x > 0 ? 1u : 0u) << (i * 4 + 0);
      mw |= (v.y > 0 ? 1u : 0u) << (i * 4 + 1);
      mw |= (v.z > 0 ? 1u : 0u) << (i * 4 + 2);
      mw |= (v.w > 0 ? 1u : 0u) << (i * 4 + 3);
    }
    u32x4* d4 = reinterpret_cast<u32x4*>(sdst0);
    d4[0] = st0; d4[1] = st1; d4[2] = st2; d4[3] = st3;
    Mbuf[0][arow][acg] = mw;
  }
  __syncthreads();

  for (int jt = 0; jt < iters; ++jt) {
    const int buf = jt & 1;
    const int j0 = (jbase + jt) * 128;

    // ---- issue next iter's staging loads (land during this iter's compute)
    u32x4 st0, st1, st2, st3;
    i32x4 ad[8];
    if (jt + 1 < iters) {
      const int j1 = (jbase + jt + 1) * 128;
      const u32x4* g4 = reinterpret_cast<const u32x4*>(
          sgbase + (size_t)(j1 + scol) * 64 + shalf * 32);
      st0 = g4[0]; st1 = g4[1]; st2 = g4[2]; st3 = g4[3];
      const i32x4* a4 = reinterpret_cast<const i32x4*>(agbase + j1);
#pragma unroll
      for (int i = 0; i < 8; ++i) ad[i] = __builtin_nontemporal_load(a4 + i);
    }

    // ---- mask for this wave's 4 rows (broadcast uint4 reads)
    u32x4 mk[4];
#pragma unroll
    for (int g = 0; g < 4; ++g)
      mk[g] = *reinterpret_cast<const u32x4*>(&Mbuf[buf][w * 16 + q * 4 + g][0]);

    // ---- scores S[16 x 128] from staged LDS B
    const u16* Bh = &Bst[buf][0][0];
    const u16* Bl = &Bst[buf][1][0];
    float s[8][4];
#pragma unroll
    for (int nt = 0; nt < 8; ++nt) {
      const int c72 = (nt * 16 + ln) * 72 + q * 8;
      bf16x8 bh0 = *reinterpret_cast<const bf16x8*>(&Bh[c72]);
      bf16x8 bh1 = *reinterpret_cast<const bf16x8*>(&Bh[c72 + 32]);
      bf16x8 bl0 = *reinterpret_cast<const bf16x8*>(&Bl[c72]);
      bf16x8 bl1 = *reinterpret_cast<const bf16x8*>(&Bl[c72 + 32]);
      f32x4 sa;
#pragma unroll
      for (int g = 0; g < 4; ++g) sa[g] = 0.f;
      sa = mfma16(a_lo[0], bh0, sa);
      sa = mfma16(a_hi[0], bl0, sa);
      sa = mfma16(a_hi[0], bh0, sa);
      sa = mfma16(a_lo[1], bh1, sa);
      sa = mfma16(a_hi[1], bl1, sa);
      sa = mfma16(a_hi[1], bh1, sa);
      const int bitpos = (nt & 1) * 16 + ln;
#pragma unroll
      for (int g = 0; g < 4; ++g) {
        unsigned wrd = (nt >> 1) == 0   ? mk[g].x
                       : (nt >> 1) == 1 ? mk[g].y
                       : (nt >> 1) == 2 ? mk[g].z
                                        : mk[g].w;
        s[nt][g] = ((wrd >> bitpos) & 1u) ? sa[g] : NEGC;
      }
    }

    // ---- prefetch whcT kh=0 B-frags (overlap softmax)
    bf16x8 wbA[8], wbB[8];
#pragma unroll
    for (int ot = 0; ot < 8; ++ot)
      wbA[ot] = *reinterpret_cast<const bf16x8*>(
          whcT + (size_t)(ot * 16 + ln) * NN + j0 + q * 8);

    // ---- in-wave online softmax
    float mr[4];
#pragma unroll
    for (int g = 0; g < 4; ++g) mr[g] = s[0][g];
#pragma unroll
    for (int nt = 1; nt < 8; ++nt)
#pragma unroll
      for (int g = 0; g < 4; ++g) mr[g] = fmaxf(mr[g], s[nt][g]);
#pragma unroll
    for (int msk = 1; msk <= 8; msk <<= 1)
#pragma unroll
      for (int g = 0; g < 4; ++g) mr[g] = fmaxf(mr[g], __shfl_xor(mr[g], msk));

    float mn[4], alpha[4], ps[4];
#pragma unroll
    for (int g = 0; g < 4; ++g) {
      mn[g] = fmaxf(m_old[g], mr[g]);
      alpha[g] = __expf(m_old[g] - mn[g]);
      m_old[g] = mn[g];
      ps[g] = 0.f;
    }
#pragma unroll
    for (int nt = 0; nt < 8; ++nt)
#pragma unroll
      for (int g = 0; g < 4; ++g) {
        float p = __expf(s[nt][g] - mn[g]);
        ps[g] += p;
        Pbuf[w][q * 4 + g][nt * 16 + ln] = f2bf(p);
      }
#pragma unroll
    for (int msk = 1; msk <= 8; msk <<= 1)
#pragma unroll
      for (int g = 0; g < 4; ++g) ps[g] += __shfl_xor(ps[g], msk);
#pragma unroll
    for (int g = 0; g < 4; ++g) l_run[g] = l_run[g] * alpha[g] + ps[g];
#pragma unroll
    for (int ot = 0; ot < 8; ++ot)
#pragma unroll
      for (int g = 0; g < 4; ++g) oacc[ot][g] *= alpha[g];

    // ---- PV with whcT register pipeline
#pragma unroll
    for (int kh = 0; kh < 4; ++kh) {
      bf16x8* cur = (kh & 1) ? wbB : wbA;
      bf16x8* nxt = (kh & 1) ? wbA : wbB;
      if (kh < 3) {
#pragma unroll
        for (int ot = 0; ot < 8; ++ot)
          nxt[ot] = *reinterpret_cast<const bf16x8*>(
              whcT + (size_t)(ot * 16 + ln) * NN + j0 + (kh + 1) * 32 + q * 8);
      }
      bf16x8 pa = *reinterpret_cast<const bf16x8*>(
          &Pbuf[w][ln][kh * 32 + q * 8]);
#pragma unroll
      for (int ot = 0; ot < 8; ++ot)
        oacc[ot] = mfma16(pa, cur[ot], oacc[ot]);
    }

    // ---- commit next iter's staging to the other buffers, then barrier
    if (jt + 1 < iters) {
      unsigned mw = 0;
#pragma unroll
      for (int i = 0; i < 8; ++i) {
        mw |= (ad[i].x > 0 ? 1u : 0u) << (i * 4 + 0);
        mw |= (ad[i].y > 0 ? 1u : 0u) << (i * 4 + 1);
        mw |= (ad[i].z > 0 ? 1u : 0u) << (i * 4 + 2);
        mw |= (ad[i].w > 0 ? 1u : 0u) << (i * 4 + 3);
      }
      u32x4* d4 = reinterpret_cast<u32x4*>(buf ? sdst0 : sdst1);
      d4[0] = st0; d4[1] = st1; d4[2] = st2; d4[3] = st3;
      Mbuf[buf ^ 1][arow][acg] = mw;
    }
    __syncthreads();
  }

  // ---- epilogue
  if (final_write) {
#pragma unroll
    for (int ot = 0; ot < 8; ++ot)
#pragma unroll
      for (int g = 0; g < 4; ++g) {
        const int r = row0 + q * 4 + g;
        out[(size_t)r * OUTF + ot * 16 + ln] = oacc[ot][g] / l_run[g];
      }
  } else {
#pragma unroll
    for (int ot = 0; ot < 8; ++ot)
#pragma unroll
      for (int g = 0; g < 4; ++g) {
        const int r = row0 + q * 4 + g;
        Opart[((size_t)chunk * NN + r) * OUTF + ot * 16 + ln] = oacc[ot][g];
      }
    if (ln == 0) {
#pragma unroll
      for (int g = 0; g < 4; ++g) {
        const int r = row0 + q * 4 + g;
        mpart[chunk * NN + r] = m_old[g];
        lpart[chunk * NN + r] = l_run[g];
      }
    }
  }
}

// ---------------------------------------------------------------- kernel 3
__global__ __launch_bounds__(256) void combine_kernel(
    const float* __restrict__ Opart, const float* __restrict__ mpart,
    const float* __restrict__ lpart, float* __restrict__ out, int C) {
  const int idx = blockIdx.x * 256 + threadIdx.x;  // over N*OUTF
  const int row = idx >> 7;
  float M = -__builtin_inff();
  for (int c = 0; c < C; ++c) M = fmaxf(M, mpart[c * NN + row]);
  float den = 0.f, num = 0.f;
  for (int c = 0; c < C; ++c) {
    float wgt = __expf(mpart[c * NN + row] - M);
    den += lpart[c * NN + row] * wgt;
    num += Opart[(size_t)c * NN * OUTF + idx] * wgt;
  }
  out[idx] = num / den;
}

// ---------------------------------------------------------------- launch
extern "C" void kernel_launch(void* const* d_in, const int* in_sizes, int n_in,
                              void* d_out, int out_size, void* d_ws, size_t ws_size,
                              hipStream_t stream) {
  const float* h   = (const float*)d_in[0];
  const int*   adj = (const int*)d_in[1];
  const float* Ws  = (const float*)d_in[2];
  const float* Wt  = (const float*)d_in[3];
  const float* Wc  = (const float*)d_in[4];
  float* out = (float*)d_out;

  char* ws = (char*)d_ws;
  const size_t MB = 1024 * 1024;
  // ws: whs_hi|whs_lo|wht_hi|wht_lo (1MB each) | whcT (2MB)
  //     | mpart (256KB) | lpart (256KB) | Opart (C*4MB)
  u16* whs_hi = (u16*)(ws);
  u16* whs_lo = (u16*)(ws + 1 * MB);
  u16* wht_hi = (u16*)(ws + 2 * MB);
  u16* wht_lo = (u16*)(ws + 3 * MB);
  u16* whcT   = (u16*)(ws + 4 * MB);
  float* mpart = (float*)(ws + 6 * MB);
  float* lpart = (float*)(ws + 6 * MB + 256 * 1024);
  float* Opart = (float*)(ws + 6 * MB + 512 * 1024);

  // C=4 (grid 256 = 1 block/CU) if ws allows, else C=1 direct-write
  int C = 4, cshift = 2;
  if (6 * MB + 512 * 1024 + (size_t)C * NN * OUTF * sizeof(float) > ws_size) {
    C = 1; cshift = 0;
  }
  const int final_write = (C == 1) ? 1 : 0;
  const int iters = 64 / C;

  proj_kernel<<<NN / 8, 256, 0, stream>>>(h, Ws, Wt, Wc, whs_hi, whs_lo,
                                          wht_hi, wht_lo, whcT);
  attn_kernel<<<64 * C, 512, 0, stream>>>(whs_hi, whs_lo, wht_hi, wht_lo,
                                          whcT, adj, Opart, mpart, lpart,
                                          out, iters, cshift, final_write);
  if (!final_write)
    combine_kernel<<<NN * OUTF / 256, 256, 0, stream>>>(Opart, mpart, lpart,
                                                        out, C);
}

// Round 9
// 449.167 us; speedup vs baseline: 1.2994x; 1.2994x over previous
//
#include <hip/hip_runtime.h>

// GraphAttentionLayer on MI355X (gfx950)
// N=8192, IN_F=128, N_HID=64, OUT_F=128
//
// R9: revert to the R5/R6-PROVEN K-loop pattern (ALL LDS buffers
// double-buffered, ONE __syncthreads per iter, commits target buf^1),
// which survived harness graph-replay; R8's single-buffer/2-barrier
// variant failed post-timing revalidation. LDS fits double buffers by
// shrinking the tile: CT=64 cols/iter, 64 Q-rows/block (256 thr, 4 waves).
//   Bst[2][2][64][72]  wht hi/lo, pad-72 -> QK B-frag reads 2-way (free)
//   Wst[2][128][64]    whcT slice, chunk-XOR swizzle -> PV-B reads 4-way
//   Pbuf[4][16][72]    P transpose (wave-private, single is safe in-wave)
//   Mbuf[2][64][4]u16  packed adj bits
//   total 78 KB -> 2 blocks/CU: the other block computes through each
//   barrier drain (m114 co-scheduling) — fixes R6's 1-block/CU stall.
// All staging loads (wht/whcT/adj) issue one iter ahead into regs,
// coalesced; adj is the only real HBM stream (256 MB, read once).

#define NN 8192
#define INF_ 128
#define NHID 64
#define OUTF 128
#define NEGC -9.0e15f

typedef unsigned short u16;
typedef __attribute__((ext_vector_type(8))) short bf16x8;
typedef __attribute__((ext_vector_type(4))) float f32x4;
typedef __attribute__((ext_vector_type(4))) int i32x4;
typedef __attribute__((ext_vector_type(4))) unsigned u32x4;

static __device__ __forceinline__ u16 f2bf(float x) {
  union { float f; unsigned u; } v; v.f = x;
  unsigned lsb = (v.u >> 16) & 1u;
  v.u += 0x7fffu + lsb;            // round-to-nearest-even
  return (u16)(v.u >> 16);
}
static __device__ __forceinline__ float bf2f(u16 h) {
  union { float f; unsigned u; } v; v.u = ((unsigned)h) << 16;
  return v.f;
}
static __device__ __forceinline__ f32x4 mfma16(bf16x8 a, bf16x8 b, f32x4 c) {
  return __builtin_amdgcn_mfma_f32_16x16x32_bf16(a, b, c, 0, 0, 0);
}

// ---------------------------------------------------------------- kernel 1
__global__ __launch_bounds__(256) void proj_kernel(
    const float* __restrict__ h, const float* __restrict__ Ws,
    const float* __restrict__ Wt, const float* __restrict__ Wc,
    u16* __restrict__ whs_hi, u16* __restrict__ whs_lo,
    u16* __restrict__ wht_hi, u16* __restrict__ wht_lo,
    u16* __restrict__ whcT) {
  __shared__ f32x4 hbuf[8][32];   // 8 rows x 128 k
  const int tid = threadIdx.x;
  const int r0 = blockIdx.x * 8;
  hbuf[tid >> 5][tid & 31] =
      reinterpret_cast<const f32x4*>(h)[(size_t)r0 * 32 + tid];
  __syncthreads();

  float acc[8];
#pragma unroll
  for (int r = 0; r < 8; ++r) acc[r] = 0.f;

  if (tid < 128) {
    const float* W = (tid < 64) ? (Ws + tid) : (Wt + (tid - 64));
#pragma unroll 4
    for (int k4 = 0; k4 < 32; ++k4) {
      float w0 = W[(k4 * 4 + 0) * NHID];
      float w1 = W[(k4 * 4 + 1) * NHID];
      float w2 = W[(k4 * 4 + 2) * NHID];
      float w3 = W[(k4 * 4 + 3) * NHID];
#pragma unroll
      for (int r = 0; r < 8; ++r) {
        f32x4 hv = hbuf[r][k4];
        acc[r] += hv.x * w0 + hv.y * w1 + hv.z * w2 + hv.w * w3;
      }
    }
    const int col = tid & 63;
    u16* hi = (tid < 64) ? whs_hi : wht_hi;
    u16* lo = (tid < 64) ? whs_lo : wht_lo;
#pragma unroll
    for (int r = 0; r < 8; ++r) {
      float v = acc[r];
      u16 hb = f2bf(v);
      hi[(size_t)(r0 + r) * NHID + col] = hb;
      lo[(size_t)(r0 + r) * NHID + col] = f2bf(v - bf2f(hb));
    }
  } else {
    const int col = tid - 128;
    const float* W = Wc + col;
#pragma unroll 4
    for (int k4 = 0; k4 < 32; ++k4) {
      float w0 = W[(k4 * 4 + 0) * OUTF];
      float w1 = W[(k4 * 4 + 1) * OUTF];
      float w2 = W[(k4 * 4 + 2) * OUTF];
      float w3 = W[(k4 * 4 + 3) * OUTF];
#pragma unroll
      for (int r = 0; r < 8; ++r) {
        f32x4 hv = hbuf[r][k4];
        acc[r] += hv.x * w0 + hv.y * w1 + hv.z * w2 + hv.w * w3;
      }
    }
    union { u16 s[8]; u32x4 v; } pk;
#pragma unroll
    for (int r = 0; r < 8; ++r) pk.s[r] = f2bf(acc[r]);
    *reinterpret_cast<u32x4*>(whcT + (size_t)col * NN + r0) = pk.v;
  }
}

// ---------------------------------------------------------------- kernel 2
// 4 waves x 16 rows = 64 rows/block, CT=64 cols/iter, 2 blocks/CU.
// chunk = blockIdx & (C-1), rb = blockIdx >> cshift.
__global__ __launch_bounds__(256, 2) void attn_kernel(
    const u16* __restrict__ whs_hi, const u16* __restrict__ whs_lo,
    const u16* __restrict__ wht_hi, const u16* __restrict__ wht_lo,
    const u16* __restrict__ whcT, const int* __restrict__ adj,
    float* __restrict__ Opart, float* __restrict__ mpart,
    float* __restrict__ lpart, float* __restrict__ out,
    int iters, int cshift, int final_write) {
  __shared__ __align__(16) u16 Bst[2][2][64 * 72];   // 36864 B (wht hi/lo)
  __shared__ __align__(16) u16 Wst[2][128 * 64];     // 32768 B (whcT, swizzled)
  __shared__ __align__(16) u16 Pbuf[4][16][72];      //  9216 B
  __shared__ __align__(16) u16 Mbuf[2][64][4];       //  1024 B

  const int tid = threadIdx.x;
  const int w = tid >> 6;       // wave 0..3
  const int lane = tid & 63;
  const int q = lane >> 4;
  const int ln = lane & 15;
  const int chunk = blockIdx.x & ((1 << cshift) - 1);
  const int rb = blockIdx.x >> cshift;
  const int rowB = rb * 64;
  const int row0 = rowB + w * 16;

  // staging roles (fully coalesced global reads, 64 B/thread each stream)
  const int bcol = tid >> 2;                 // wht: col 0..63
  const int bsh = (tid >> 1) & 1;            //      hi/lo
  const int bkh = tid & 1;                   //      k-half
  const u16* bg = (bsh ? wht_lo : wht_hi) + (size_t)bcol * NHID + bkh * 32;
  const int wocol = tid >> 1;                // whcT: ocol 0..127
  const int wjh = tid & 1;                   //       j-half
  const u16* wg = whcT + (size_t)wocol * NN + wjh * 32;
  const int wsw0 = ((2 * wjh + 0) ^ (wocol & 3)) * 16;  // swizzled chunks
  const int wsw1 = ((2 * wjh + 1) ^ (wocol & 3)) * 16;
  const int arow = tid >> 2;                 // adj: row 0..63
  const int agrp = tid & 3;                  //      16-col group
  const int* ag = adj + (size_t)(rowB + arow) * NN + agrp * 16;

  // loop-invariant A-fragments (Whs rows row0+ln, 64 k hi/lo)
  bf16x8 a_hi[2], a_lo[2];
#pragma unroll
  for (int kh = 0; kh < 2; ++kh) {
    a_hi[kh] = *reinterpret_cast<const bf16x8*>(
        whs_hi + (size_t)(row0 + ln) * NHID + kh * 32 + q * 8);
    a_lo[kh] = *reinterpret_cast<const bf16x8*>(
        whs_lo + (size_t)(row0 + ln) * NHID + kh * 32 + q * 8);
  }

  f32x4 oacc[8];
#pragma unroll
  for (int ot = 0; ot < 8; ++ot)
#pragma unroll
    for (int g = 0; g < 4; ++g) oacc[ot][g] = 0.f;

  float m_old[4], l_run[4];
#pragma unroll
  for (int g = 0; g < 4; ++g) { m_old[g] = -__builtin_inff(); l_run[g] = 0.f; }

  const int jbase = chunk * iters;   // in 64-col tiles

  // ---- preload tile 0 into buffer 0
  {
    const size_t j0 = (size_t)jbase * 64;
    const u32x4* p = reinterpret_cast<const u32x4*>(bg + j0 * NHID);
    u32x4 b0 = p[0], b1 = p[1], b2 = p[2], b3 = p[3];
    const u32x4* pw = reinterpret_cast<const u32x4*>(wg + j0);
    u32x4 w0 = pw[0], w1 = pw[1], w2 = pw[2], w3 = pw[3];
    const i32x4* pa = reinterpret_cast<const i32x4*>(ag + j0);
    i32x4 a0 = __builtin_nontemporal_load(pa + 0);
    i32x4 a1 = __builtin_nontemporal_load(pa + 1);
    i32x4 a2 = __builtin_nontemporal_load(pa + 2);
    i32x4 a3 = __builtin_nontemporal_load(pa + 3);
    u32x4* d = reinterpret_cast<u32x4*>(&Bst[0][bsh][bcol * 72 + bkh * 32]);
    d[0] = b0; d[1] = b1; d[2] = b2; d[3] = b3;
    u32x4* e0 = reinterpret_cast<u32x4*>(&Wst[0][wocol * 64 + wsw0]);
    e0[0] = w0; e0[1] = w1;
    u32x4* e1 = reinterpret_cast<u32x4*>(&Wst[0][wocol * 64 + wsw1]);
    e1[0] = w2; e1[1] = w3;
    unsigned mw = 0;
    mw |= (a0.x>0?1u:0u)<<0  | (a0.y>0?1u:0u)<<1  | (a0.z>0?1u:0u)<<2  | (a0.w>0?1u:0u)<<3;
    mw |= (a1.x>0?1u:0u)<<4  | (a1.y>0?1u:0u)<<5  | (a1.z>0?1u:0u)<<6  | (a1.w>0?1u:0u)<<7;
    mw |= (a2.x>0?1u:0u)<<8  | (a2.y>0?1u:0u)<<9  | (a2.z>0?1u:0u)<<10 | (a2.w>0?1u:0u)<<11;
    mw |= (a3.x>0?1u:0u)<<12 | (a3.y>0?1u:0u)<<13 | (a3.z>0?1u:0u)<<14 | (a3.w>0?1u:0u)<<15;
    Mbuf[0][arow][agrp] = (u16)mw;
  }
  __syncthreads();

  for (int jt = 0; jt < iters; ++jt) {
    const int buf = jt & 1;

    // ---- issue next tile's staging loads (land during this iter's compute)
    u32x4 sb0, sb1, sb2, sb3, sw0, sw1, sw2, sw3;
    i32x4 ad0, ad1, ad2, ad3;
    if (jt + 1 < iters) {
      const size_t j1 = (size_t)(jbase + jt + 1) * 64;
      const u32x4* p = reinterpret_cast<const u32x4*>(bg + j1 * NHID);
      sb0 = p[0]; sb1 = p[1]; sb2 = p[2]; sb3 = p[3];
      const u32x4* pw = reinterpret_cast<const u32x4*>(wg + j1);
      sw0 = pw[0]; sw1 = pw[1]; sw2 = pw[2]; sw3 = pw[3];
      const i32x4* pa = reinterpret_cast<const i32x4*>(ag + j1);
      ad0 = __builtin_nontemporal_load(pa + 0);
      ad1 = __builtin_nontemporal_load(pa + 1);
      ad2 = __builtin_nontemporal_load(pa + 2);
      ad3 = __builtin_nontemporal_load(pa + 3);
    }

    // ---- masks for this wave's 4 rows (4 x u16 per row)
    unsigned mk01[4], mk23[4];
#pragma unroll
    for (int g = 0; g < 4; ++g) {
      const unsigned* mrow = reinterpret_cast<const unsigned*>(
          &Mbuf[buf][w * 16 + q * 4 + g][0]);
      mk01[g] = mrow[0];
      mk23[g] = mrow[1];
    }

    // ---- scores S[16 x 64] from staged LDS (hi/lo split, 6 MFMA per nt)
    const u16* Bh = &Bst[buf][0][0];
    const u16* Bl = &Bst[buf][1][0];
    float s[4][4];
#pragma unroll
    for (int nt = 0; nt < 4; ++nt) {
      const int base = (nt * 16 + ln) * 72 + q * 8;
      bf16x8 bh0 = *reinterpret_cast<const bf16x8*>(&Bh[base]);
      bf16x8 bh1 = *reinterpret_cast<const bf16x8*>(&Bh[base + 32]);
      bf16x8 bl0 = *reinterpret_cast<const bf16x8*>(&Bl[base]);
      bf16x8 bl1 = *reinterpret_cast<const bf16x8*>(&Bl[base + 32]);
      f32x4 sa;
#pragma unroll
      for (int g = 0; g < 4; ++g) sa[g] = 0.f;
      sa = mfma16(a_lo[0], bh0, sa);
      sa = mfma16(a_hi[0], bl0, sa);
      sa = mfma16(a_hi[0], bh0, sa);
      sa = mfma16(a_lo[1], bh1, sa);
      sa = mfma16(a_hi[1], bl1, sa);
      sa = mfma16(a_hi[1], bh1, sa);
#pragma unroll
      for (int g = 0; g < 4; ++g) {
        unsigned wrd = (nt == 0) ? (mk01[g] & 0xffffu)
                     : (nt == 1) ? (mk01[g] >> 16)
                     : (nt == 2) ? (mk23[g] & 0xffffu)
                                 : (mk23[g] >> 16);
        s[nt][g] = ((wrd >> ln) & 1u) ? sa[g] : NEGC;
      }
    }

    // ---- in-wave online softmax (row r=q*4+g across 16 ln-lanes)
    float mr[4];
#pragma unroll
    for (int g = 0; g < 4; ++g)
      mr[g] = fmaxf(fmaxf(s[0][g], s[1][g]), fmaxf(s[2][g], s[3][g]));
#pragma unroll
    for (int msk = 1; msk <= 8; msk <<= 1)
#pragma unroll
      for (int g = 0; g < 4; ++g) mr[g] = fmaxf(mr[g], __shfl_xor(mr[g], msk));

    float mn[4], alpha[4], ps[4];
#pragma unroll
    for (int g = 0; g < 4; ++g) {
      mn[g] = fmaxf(m_old[g], mr[g]);
      alpha[g] = __expf(m_old[g] - mn[g]);
      m_old[g] = mn[g];
      ps[g] = 0.f;
    }
#pragma unroll
    for (int nt = 0; nt < 4; ++nt)
#pragma unroll
      for (int g = 0; g < 4; ++g) {
        float p = __expf(s[nt][g] - mn[g]);
        ps[g] += p;
        Pbuf[w][q * 4 + g][nt * 16 + ln] = f2bf(p);
      }
#pragma unroll
    for (int msk = 1; msk <= 8; msk <<= 1)
#pragma unroll
      for (int g = 0; g < 4; ++g) ps[g] += __shfl_xor(ps[g], msk);
#pragma unroll
    for (int g = 0; g < 4; ++g) l_run[g] = l_run[g] * alpha[g] + ps[g];
#pragma unroll
    for (int ot = 0; ot < 8; ++ot)
#pragma unroll
      for (int g = 0; g < 4; ++g) oacc[ot][g] *= alpha[g];

    // ---- PV from LDS (Pbuf A-frags; swizzled Wst B-frags)
#pragma unroll
    for (int kh = 0; kh < 2; ++kh) {
      bf16x8 pa = *reinterpret_cast<const bf16x8*>(
          &Pbuf[w][ln][kh * 32 + q * 8]);
      const int c = kh * 2 + (q >> 1);
      const int sub = (q & 1) * 8;
#pragma unroll
      for (int ot = 0; ot < 8; ++ot) {
        const int ocol = ot * 16 + ln;
        bf16x8 wb = *reinterpret_cast<const bf16x8*>(
            &Wst[buf][ocol * 64 + ((c ^ (ocol & 3)) << 4) + sub]);
        oacc[ot] = mfma16(pa, wb, oacc[ot]);
      }
    }

    // ---- commit next tile into buf^1 (all double-buffered), ONE barrier
    if (jt + 1 < iters) {
      const int nb = buf ^ 1;
      u32x4* d = reinterpret_cast<u32x4*>(&Bst[nb][bsh][bcol * 72 + bkh * 32]);
      d[0] = sb0; d[1] = sb1; d[2] = sb2; d[3] = sb3;
      u32x4* e0 = reinterpret_cast<u32x4*>(&Wst[nb][wocol * 64 + wsw0]);
      e0[0] = sw0; e0[1] = sw1;
      u32x4* e1 = reinterpret_cast<u32x4*>(&Wst[nb][wocol * 64 + wsw1]);
      e1[0] = sw2; e1[1] = sw3;
      unsigned mw = 0;
      mw |= (ad0.x>0?1u:0u)<<0  | (ad0.y>0?1u:0u)<<1  | (ad0.z>0?1u:0u)<<2  | (ad0.w>0?1u:0u)<<3;
      mw |= (ad1.x>0?1u:0u)<<4  | (ad1.y>0?1u:0u)<<5  | (ad1.z>0?1u:0u)<<6  | (ad1.w>0?1u:0u)<<7;
      mw |= (ad2.x>0?1u:0u)<<8  | (ad2.y>0?1u:0u)<<9  | (ad2.z>0?1u:0u)<<10 | (ad2.w>0?1u:0u)<<11;
      mw |= (ad3.x>0?1u:0u)<<12 | (ad3.y>0?1u:0u)<<13 | (ad3.z>0?1u:0u)<<14 | (ad3.w>0?1u:0u)<<15;
      Mbuf[buf ^ 1][arow][agrp] = (u16)mw;
    }
    __syncthreads();
  }

  // ---- epilogue
  if (final_write) {
#pragma unroll
    for (int ot = 0; ot < 8; ++ot)
#pragma unroll
      for (int g = 0; g < 4; ++g) {
        const int r = row0 + q * 4 + g;
        out[(size_t)r * OUTF + ot * 16 + ln] = oacc[ot][g] / l_run[g];
      }
  } else {
#pragma unroll
    for (int ot = 0; ot < 8; ++ot)
#pragma unroll
      for (int g = 0; g < 4; ++g) {
        const int r = row0 + q * 4 + g;
        Opart[((size_t)chunk * NN + r) * OUTF + ot * 16 + ln] = oacc[ot][g];
      }
    if (ln == 0) {
#pragma unroll
      for (int g = 0; g < 4; ++g) {
        const int r = row0 + q * 4 + g;
        mpart[chunk * NN + r] = m_old[g];
        lpart[chunk * NN + r] = l_run[g];
      }
    }
  }
}

// ---------------------------------------------------------------- kernel 3
__global__ __launch_bounds__(256) void combine_kernel(
    const float* __restrict__ Opart, const float* __restrict__ mpart,
    const float* __restrict__ lpart, float* __restrict__ out, int C) {
  const int idx = blockIdx.x * 256 + threadIdx.x;  // over N*OUTF
  const int row = idx >> 7;
  float M = -__builtin_inff();
  for (int c = 0; c < C; ++c) M = fmaxf(M, mpart[c * NN + row]);
  float den = 0.f, num = 0.f;
  for (int c = 0; c < C; ++c) {
    float wgt = __expf(mpart[c * NN + row] - M);
    den += lpart[c * NN + row] * wgt;
    num += Opart[(size_t)c * NN * OUTF + idx] * wgt;
  }
  out[idx] = num / den;
}

// ---------------------------------------------------------------- launch
extern "C" void kernel_launch(void* const* d_in, const int* in_sizes, int n_in,
                              void* d_out, int out_size, void* d_ws, size_t ws_size,
                              hipStream_t stream) {
  const float* h   = (const float*)d_in[0];
  const int*   adj = (const int*)d_in[1];
  const float* Ws  = (const float*)d_in[2];
  const float* Wt  = (const float*)d_in[3];
  const float* Wc  = (const float*)d_in[4];
  float* out = (float*)d_out;

  char* ws = (char*)d_ws;
  const size_t MB = 1024 * 1024;
  // ws: whs_hi|whs_lo|wht_hi|wht_lo (1MB each) | whcT (2MB)
  //     | mpart (256KB) | lpart (256KB) | Opart (C*4MB)
  u16* whs_hi = (u16*)(ws);
  u16* whs_lo = (u16*)(ws + 1 * MB);
  u16* wht_hi = (u16*)(ws + 2 * MB);
  u16* wht_lo = (u16*)(ws + 3 * MB);
  u16* whcT   = (u16*)(ws + 4 * MB);
  float* mpart = (float*)(ws + 6 * MB);
  float* lpart = (float*)(ws + 6 * MB + 256 * 1024);
  float* Opart = (float*)(ws + 6 * MB + 512 * 1024);

  // C=4 -> grid 512 = 2 blocks/CU; C=1 fallback writes out directly.
  int C = 4, cshift = 2;
  if (6 * MB + 512 * 1024 + (size_t)C * NN * OUTF * sizeof(float) > ws_size) {
    C = 1; cshift = 0;
  }
  const int final_write = (C == 1) ? 1 : 0;
  const int iters = NN / (C * 64);     // 64-col tiles per chunk

  proj_kernel<<<NN / 8, 256, 0, stream>>>(h, Ws, Wt, Wc, whs_hi, whs_lo,
                                          wht_hi, wht_lo, whcT);
  attn_kernel<<<(NN / 64) * C, 256, 0, stream>>>(
      whs_hi, whs_lo, wht_hi, wht_lo, whcT, adj, Opart, mpart, lpart, out,
      iters, cshift, final_write);
  if (!final_write)
    combine_kernel<<<NN * OUTF / 256, 256, 0, stream>>>(Opart, mpart, lpart,
                                                        out, C);
}